// Round 16
// baseline (157.574 us; speedup 1.0000x reference)
//
#include <hip/hip_runtime.h>
#include <hip/hip_fp16.h>
#include <math.h>

#define NNODE 22
#define FIN 16
#define C1 128
#define C2 64
#define C3 32
#define GPB 2              // graphs per block
#define RPAD 24            // padded rows per graph (rows 22,23 = pad)
#define RP 48              // total padded rows = 3 M-tiles of 16
#define MT 3
#define TGS 56             // Tg column stride (ushorts): 112B = 16B-aligned, 2-way banks
#define TSS 52             // Tst column stride (floats): 208B = 16B-aligned, 2-way banks
#define THREADS 256

typedef __attribute__((ext_vector_type(8))) short short8;
typedef __attribute__((ext_vector_type(8))) _Float16 half8;
typedef __attribute__((ext_vector_type(4))) float f32x4;
typedef __attribute__((ext_vector_type(4))) int i32x4;

#define WS2_BYTES (64*64*16)
#define WS1_OFF   WS2_BYTES

// ---- fp16 helpers (all RNE via documented intrinsics; asm cvt failed r7-8) ----
__device__ __forceinline__ float h2f(unsigned short u){
    return __half2float(__ushort_as_half(u));
}
__device__ __forceinline__ unsigned int pkh2(float a, float b){   // 2x fp16 RNE pack
    __half2 h = __float22half2_rn(float2{a, b});                  // a -> low 16
    unsigned int r;
    __builtin_memcpy(&r, &h, 4);
    return r;
}
// fp16 split (scalar, prep): hi RNE fp16, lo = RNE fp16 of residual (~2^-22 rel)
__device__ __forceinline__ void fsplit_h(float f, unsigned short& hi, unsigned short& lo){
    __half h = __float2half_rn(f);
    hi = __half_as_ushort(h);
    lo = __half_as_ushort(__float2half_rn(f - __half2float(h)));
}
// split pair (a,b) -> fp16 hi/lo dwords, a in low half
__device__ __forceinline__ void fsplit2h(float a, float b, unsigned int& hpk, unsigned int& lpk){
    hpk = pkh2(a, b);
    lpk = pkh2(a - h2f((unsigned short)hpk), b - h2f((unsigned short)(hpk >> 16)));
}
// split 8 fp32 into fp16 hi/lo half8
__device__ __forceinline__ void split8h(f32x4 p0, f32x4 p1, half8& h, half8& l){
    unsigned int h01 = pkh2(p0[0], p0[1]);
    unsigned int h23 = pkh2(p0[2], p0[3]);
    unsigned int h45 = pkh2(p1[0], p1[1]);
    unsigned int h67 = pkh2(p1[2], p1[3]);
    unsigned int l01 = pkh2(p0[0] - h2f((unsigned short)h01), p0[1] - h2f((unsigned short)(h01 >> 16)));
    unsigned int l23 = pkh2(p0[2] - h2f((unsigned short)h23), p0[3] - h2f((unsigned short)(h23 >> 16)));
    unsigned int l45 = pkh2(p1[0] - h2f((unsigned short)h45), p1[1] - h2f((unsigned short)(h45 >> 16)));
    unsigned int l67 = pkh2(p1[2] - h2f((unsigned short)h67), p1[3] - h2f((unsigned short)(h67 >> 16)));
    i32x4 hv = {(int)h01, (int)h23, (int)h45, (int)h67};
    i32x4 lv = {(int)l01, (int)l23, (int)l45, (int)l67};
    h = __builtin_bit_cast(half8, hv);
    l = __builtin_bit_cast(half8, lv);
}

// ---------------- setup kernel: weight fragments (all fp16 hi/lo) ----------------
__global__ void prep_frags(const float* __restrict__ w1,
                           const float* __restrict__ w2g,
                           const float* __restrict__ w2s,
                           unsigned char* __restrict__ ws)
{
    const int t = blockIdx.x * 256 + threadIdx.x;   // 0..5119
    if (t < 4096) {                                  // W2: f = ((wv*2+nt)*4+kt)*2+h
        const int lane = t & 63, f = t >> 6;
        const int h = f & 1, kt = (f >> 1) & 3, nt = (f >> 3) & 1, wv = f >> 4;
        const int lr = lane & 15, lg = lane >> 4;
        const int col = wv*32 + nt*16 + lr;
        const float* src = (col < C2) ? (w2g + col) : (w2s + (col - C2));
        short8 out;
        #pragma unroll
        for (int e = 0; e < 8; ++e) {
            // H1 physical col p = kt*32 + w holds logical col (w>>1) + 16*(w&1)
            const int w = lg*8 + e;
            const int kl = kt*32 + (w >> 1) + ((w & 1) << 4);
            unsigned short hh, ll;
            fsplit_h(src[(size_t)kl * C2], hh, ll);
            out[e] = (short)(h ? ll : hh);
        }
        *(short8*)(ws + (size_t)f*1024 + lane*16) = out;
    } else if (t < 5120) {                           // W1: f = (wv*2+nt)*2+h (no perm)
        const int u = t - 4096;
        const int lane = u & 63, f = u >> 6;
        const int h = f & 1, nt = (f >> 1) & 1, wv = f >> 2;
        const int lr = lane & 15, lg = lane >> 4;
        short8 out = {0,0,0,0,0,0,0,0};
        if (lane < 32) {
            const int col = wv*32 + nt*16 + lr;
            #pragma unroll
            for (int e = 0; e < 8; ++e) {
                unsigned short hh, ll;
                fsplit_h(w1[(size_t)(lg*8 + e) * C1 + col], hh, ll);
                out[e] = (short)(h ? ll : hh);
            }
        }
        *(short8*)(ws + WS1_OFF + (size_t)f*1024 + lane*16) = out;
    }
}

// ---------------- main fused kernel ----------------
// LDS: EXACTLY 32,768 B -> 5 blocks/CU (1024-B alloc granule; 163840/5 = 32768).
// Tst drops its +8 pad: the single overread (g4=1,col=63,lg=3 -> floats 3328..3331)
// lands in R2 = finite garbage feeding only n>=28 rows, masked by n<NNODE.
// sPool/sG1 alias into H1 (dead after phase 3; barriers separate all uses).
union __align__(16) R1u {
    struct { float A[GPB*NNODE*NNODE]; float X[GPB*NNODE*FIN]; } stg;  // 6688 B
    float Tst[C2*TSS];                                                  // 13312 B
};
union __align__(16) R2u {
    struct { unsigned short hi[RP][FIN]; unsigned short lo[RP][FIN]; } ax; // 3072 B (fp16 bits)
    unsigned short tg[C2*TGS];                                             // 7168 B (fp16 single)
};

__global__ __launch_bounds__(THREADS, 5) void gnn_fused(
    const float* __restrict__ x, const float* __restrict__ a,
    const float* __restrict__ b1, const float* __restrict__ b2,
    const float* __restrict__ wf1, const float* __restrict__ bf1,
    const float* __restrict__ wf2, const float* __restrict__ bf2,
    const unsigned char* __restrict__ ws,
    float* __restrict__ out)
{
    __shared__ R1u R1;                                   // 13312 B
    __shared__ R2u R2;                                   // 7168 B
    __shared__ __align__(16) unsigned short H1[RP*C1];   // 12288 B fp16 (interleaved+swz)
    // total = 32768 B exactly -> 5 blocks/CU
    float* sPool = (float*)H1;                // [GPB][C2], used phases 4-6 (H1 dead)
    float* sG1   = (float*)H1 + GPB*C2;       // [GPB][C3], used phase 6

    const int tid  = threadIdx.x;
    const int lane = tid & 63;
    const int wv   = tid >> 6;
    const int lr   = lane & 15;
    const int lg   = lane >> 4;

    // ---- stage A, X fp32 (float4 coalesced) ----
    const float* ga = a + (size_t)blockIdx.x * (GPB*NNODE*NNODE);
    const float* gx = x + (size_t)blockIdx.x * (GPB*NNODE*FIN);
    if (tid < (GPB*NNODE*NNODE)/4) ((float4*)R1.stg.A)[tid] = ((const float4*)ga)[tid];
    if (tid < (GPB*NNODE*FIN)/4)   ((float4*)R1.stg.X)[tid] = ((const float4*)gx)[tid];
    __syncthreads();

    // ---- A-operand fragments fp16 hi/lo in registers (phases 1 and 4) ----
    const int g1 = wv & 1;
    half8 ah[2], al[2];
    #pragma unroll
    for (int m = 0; m < 2; ++m) {
        int row = lr + 16*m; if (row >= NNODE) row = NNODE-1;   // clamped rows discarded
        const float* src = R1.stg.A + g1*(NNODE*NNODE) + row*NNODE;
        f32x4 p0, p1;
        #pragma unroll
        for (int e = 0; e < 4; ++e) {
            const int k0 = lg*8 + e, k1 = lg*8 + 4 + e;
            p0[e] = (k0 < NNODE) ? src[k0] : 0.f;
            p1[e] = (k1 < NNODE) ? src[k1] : 0.f;
        }
        split8h(p0, p1, ah[m], al[m]);
    }

    // ---- Phase 1: AX = A @ X via fp16x3 MFMA; rows g*24+n, pad rows zeroed ----
    {
        f32x4 p0, p1;
        #pragma unroll
        for (int e = 0; e < 4; ++e) {
            const int k0 = lg*8 + e, k1 = lg*8 + 4 + e;
            p0[e] = (k0 < NNODE) ? R1.stg.X[g1*(NNODE*FIN) + k0*FIN + lr] : 0.f;
            p1[e] = (k1 < NNODE) ? R1.stg.X[g1*(NNODE*FIN) + k1*FIN + lr] : 0.f;
        }
        half8 xh, xl;
        split8h(p0, p1, xh, xl);
        const int m1 = wv >> 1;
        f32x4 d = {0.f,0.f,0.f,0.f};
        d = __builtin_amdgcn_mfma_f32_16x16x32_f16(ah[m1], xh, d, 0, 0, 0);
        d = __builtin_amdgcn_mfma_f32_16x16x32_f16(ah[m1], xl, d, 0, 0, 0);
        d = __builtin_amdgcn_mfma_f32_16x16x32_f16(al[m1], xh, d, 0, 0, 0);
        unsigned int hp01, lp01, hp23, lp23;
        fsplit2h(d[0], d[1], hp01, lp01);
        fsplit2h(d[2], d[3], hp23, lp23);
        #pragma unroll
        for (int r = 0; r < 4; ++r) {
            const int n = m1*16 + lg*4 + r;
            if (n < RPAD) {
                const unsigned int hp = (r < 2) ? hp01 : hp23;
                const unsigned int lp = (r < 2) ? lp01 : lp23;
                const int sh = (r & 1) * 16;
                R2.ax.hi[g1*RPAD + n][lr] = (n < NNODE) ? (unsigned short)(hp >> sh) : (unsigned short)0;
                R2.ax.lo[g1*RPAD + n][lr] = (n < NNODE) ? (unsigned short)(lp >> sh) : (unsigned short)0;
            }
        }
    }
    __syncthreads();

    // ---- Phase 2: H1 = relu(AX@W1+b1) via fp16x3; store fp16 INTERLEAVED b32 ----
    {
        const unsigned char* w1f = ws + WS1_OFF + (size_t)wv*4096 + lane*16;
        const half8 b1h0 = *(const half8*)(w1f + 0);
        const half8 b1l0 = *(const half8*)(w1f + 1024);
        const half8 b1h1 = *(const half8*)(w1f + 2048);
        const half8 b1l1 = *(const half8*)(w1f + 3072);
        const float bb10 = b1[wv*32 + lr];
        const float bb11 = b1[wv*32 + 16 + lr];
        const int p0c = wv*32 + 2*lr;   // physical col pair (p0c, p0c+1)
        #pragma unroll
        for (int mt = 0; mt < MT; ++mt) {
            half8 axh = {0,0,0,0,0,0,0,0}, axl = {0,0,0,0,0,0,0,0};
            if (lane < 32) {   // K=16 padded to 32
                axh = *(const half8*)&R2.ax.hi[mt*16 + lr][lg*8];
                axl = *(const half8*)&R2.ax.lo[mt*16 + lr][lg*8];
            }
            f32x4 a0 = {0.f,0.f,0.f,0.f}, a1 = {0.f,0.f,0.f,0.f};
            a0 = __builtin_amdgcn_mfma_f32_16x16x32_f16(axh, b1h0, a0, 0, 0, 0);
            a0 = __builtin_amdgcn_mfma_f32_16x16x32_f16(axh, b1l0, a0, 0, 0, 0);
            a0 = __builtin_amdgcn_mfma_f32_16x16x32_f16(axl, b1h0, a0, 0, 0, 0);
            a1 = __builtin_amdgcn_mfma_f32_16x16x32_f16(axh, b1h1, a1, 0, 0, 0);
            a1 = __builtin_amdgcn_mfma_f32_16x16x32_f16(axh, b1l1, a1, 0, 0, 0);
            a1 = __builtin_amdgcn_mfma_f32_16x16x32_f16(axl, b1h1, a1, 0, 0, 0);
            #pragma unroll
            for (int r = 0; r < 4; ++r) {
                const int row = mt*16 + lg*4 + r;    // all 48 rows (pads = relu(b1), finite)
                float v0 = a0[r] + bb10; v0 = v0 > 0.f ? v0 : 0.f;
                float v1 = a1[r] + bb11; v1 = v1 > 0.f ? v1 : 0.f;
                const int idx = row*C1 + (p0c ^ ((row & 7) << 3));
                *(unsigned int*)&H1[idx] = pkh2(v0, v1);   // v0 -> low = physical p0c
            }
        }
    }
    __syncthreads();

    // ---- Phase 3: T = H1 @ [w2g|w2s], fp16 MFMA x2 products (dominant GEMM) ----
    {
        f32x4 acc[MT][2];
        #pragma unroll
        for (int mt = 0; mt < MT; ++mt) {
            acc[mt][0] = (f32x4){0.f,0.f,0.f,0.f};
            acc[mt][1] = (f32x4){0.f,0.f,0.f,0.f};
        }
        const unsigned char* w2f = ws + (size_t)wv*16384 + lane*16;
        const int swz = (lr & 7) << 3;
        #pragma unroll
        for (int kt = 0; kt < 4; ++kt) {
            const unsigned char* wk = w2f + kt*2048;
            const half8 w0h  = *(const half8*)(wk + 0);
            const half8 w0l  = *(const half8*)(wk + 1024);
            const half8 w1h_ = *(const half8*)(wk + 8192);
            const half8 w1l_ = *(const half8*)(wk + 8192 + 1024);
            #pragma unroll
            for (int mt = 0; mt < MT; ++mt) {
                const int uoff = (mt*16 + lr)*C1 + ((kt*32 + lg*8) ^ swz);
                const half8 hh = *(const half8*)&H1[uoff];
                acc[mt][0] = __builtin_amdgcn_mfma_f32_16x16x32_f16(hh, w0h,  acc[mt][0], 0, 0, 0);
                acc[mt][0] = __builtin_amdgcn_mfma_f32_16x16x32_f16(hh, w0l,  acc[mt][0], 0, 0, 0);
                acc[mt][1] = __builtin_amdgcn_mfma_f32_16x16x32_f16(hh, w1h_, acc[mt][1], 0, 0, 0);
                acc[mt][1] = __builtin_amdgcn_mfma_f32_16x16x32_f16(hh, w1l_, acc[mt][1], 0, 0, 0);
            }
        }
        __syncthreads();   // all H1 reads done -> overwrite unions with T
        if (wv < 2) {
            // cols 0..63 = Tg: fp16 SINGLE, 4 consecutive padded rows -> one b64 write
            #pragma unroll
            for (int mt = 0; mt < MT; ++mt) {
                const int cr0 = mt*16 + lg*4;
                #pragma unroll
                for (int nt = 0; nt < 2; ++nt) {
                    const int col = wv*32 + nt*16 + lr;
                    uint2 hv;
                    hv.x = pkh2(acc[mt][nt][0], acc[mt][nt][1]);
                    hv.y = pkh2(acc[mt][nt][2], acc[mt][nt][3]);
                    *(uint2*)&R2.tg[col*TGS + cr0] = hv;
                }
            }
        } else {
            // cols 64..127 = Ts: transposed fp32, float4 per 4 rows
            #pragma unroll
            for (int mt = 0; mt < MT; ++mt) {
                const int cr0 = mt*16 + lg*4;
                #pragma unroll
                for (int nt = 0; nt < 2; ++nt) {
                    const int col = (wv-2)*32 + nt*16 + lr;
                    *(f32x4*)&R1.Tst[col*TSS + cr0] = acc[mt][nt];
                }
            }
        }
    }
    __syncthreads();

    // ---- Phase 4+5: H2 = relu(A@Tg + Ts + b2); pool. acc init = Ts ----
    {
        const int g4 = wv & 1;
        const int ntBase = (wv >> 1) * 2;
        float pool[2] = {0.f, 0.f};
        #pragma unroll
        for (int ntI = 0; ntI < 2; ++ntI) {
            const int col = (ntBase + ntI)*16 + lr;
            const float* tbase = &R1.Tst[col*TSS + g4*RPAD];
            f32x4 acc4[2];
            acc4[0] = *(const f32x4*)(tbase + lg*4);
            acc4[1] = *(const f32x4*)(tbase + 16 + lg*4);   // n>=22 garbage (incl. the
                                                            // col=63 spill into R2), masked
            half8 bh = {0,0,0,0,0,0,0,0};
            if (lg < 3) {   // k=24..31 would alias other graph: keep zero regs
                bh = *(const half8*)&R2.tg[col*TGS + g4*RPAD + lg*8];
            }
            #pragma unroll
            for (int m = 0; m < 2; ++m) {
                acc4[m] = __builtin_amdgcn_mfma_f32_16x16x32_f16(ah[m], bh, acc4[m], 0, 0, 0);
                acc4[m] = __builtin_amdgcn_mfma_f32_16x16x32_f16(al[m], bh, acc4[m], 0, 0, 0);
            }
            const float bb = b2[col];
            #pragma unroll
            for (int m = 0; m < 2; ++m) {
                #pragma unroll
                for (int r = 0; r < 4; ++r) {
                    const int n = m*16 + lg*4 + r;
                    if (n < NNODE) {
                        float v = acc4[m][r] + bb;
                        pool[ntI] += (v > 0.f ? v : 0.f);
                    }
                }
            }
            pool[ntI] += __shfl_xor(pool[ntI], 16);
            pool[ntI] += __shfl_xor(pool[ntI], 32);
        }
        if (lane < 16) {
            sPool[g4*C2 + (ntBase + 0)*16 + lr] = pool[0];
            sPool[g4*C2 + (ntBase + 1)*16 + lr] = pool[1];
        }
    }
    __syncthreads();

    // ---- Phase 6: head ----
    if (tid < GPB*C3) {
        const int g = tid >> 5, j = tid & 31;
        float s = bf1[j];
        #pragma unroll
        for (int c = 0; c < C2; ++c) s += sPool[g*C2 + c] * wf1[c*C3 + j];
        sG1[g*C3 + j] = s > 0.f ? s : 0.f;
    }
    __syncthreads();
    if (tid < GPB) {
        float s = bf2[0];
        #pragma unroll
        for (int j = 0; j < C3; ++j) s += sG1[tid*C3 + j] * wf2[j];
        out[(size_t)blockIdx.x*GPB + tid] = 1.f / (1.f + expf(-s));
    }
}

extern "C" void kernel_launch(void* const* d_in, const int* in_sizes, int n_in,
                              void* d_out, int out_size, void* d_ws, size_t ws_size,
                              hipStream_t stream) {
    const float* x   = (const float*)d_in[0];
    const float* a   = (const float*)d_in[1];
    const float* w1  = (const float*)d_in[2];
    const float* b1  = (const float*)d_in[3];
    const float* w2g = (const float*)d_in[4];
    const float* w2s = (const float*)d_in[5];
    const float* b2  = (const float*)d_in[6];
    const float* wf1 = (const float*)d_in[7];
    const float* bf1 = (const float*)d_in[8];
    const float* wf2 = (const float*)d_in[9];
    const float* bf2 = (const float*)d_in[10];
    float* out = (float*)d_out;
    unsigned char* ws = (unsigned char*)d_ws;

    prep_frags<<<dim3(20), dim3(256), 0, stream>>>(w1, w2g, w2s, ws);

    const int B = in_sizes[0] / (NNODE * FIN);  // 32768
    gnn_fused<<<dim3(B / GPB), dim3(THREADS), 0, stream>>>(
        x, a, b1, b2, wf1, bf1, wf2, bf2, ws, out);
}

// Round 17
// 131.698 us; speedup vs baseline: 1.1965x; 1.1965x over previous
//
#include <hip/hip_runtime.h>
#include <hip/hip_fp16.h>
#include <math.h>

#define NNODE 22
#define FIN 16
#define C1 128
#define C2 64
#define C3 32
#define GPB 2              // graphs per block
#define RPAD 24            // padded rows per graph (rows 22,23 = pad)
#define RP 48              // total padded rows = 3 M-tiles of 16
#define MT 3
#define TGS 56             // Tg/Ts column stride (ushorts): 112B = 16B-aligned, 2-way banks
#define THREADS 256

typedef __attribute__((ext_vector_type(8))) short short8;
typedef __attribute__((ext_vector_type(8))) _Float16 half8;
typedef __attribute__((ext_vector_type(4))) float f32x4;
typedef __attribute__((ext_vector_type(4))) int i32x4;

#define WS2_BYTES (64*64*16)
#define WS1_OFF   WS2_BYTES

// ---- fp16 helpers (all RNE via documented intrinsics; asm cvt failed r7-8) ----
__device__ __forceinline__ float h2f(unsigned short u){
    return __half2float(__ushort_as_half(u));
}
__device__ __forceinline__ unsigned int pkh2(float a, float b){   // 2x fp16 RNE pack
    __half2 h = __float22half2_rn(float2{a, b});                  // a -> low 16
    unsigned int r;
    __builtin_memcpy(&r, &h, 4);
    return r;
}
// fp16 split (scalar, prep): hi RNE fp16, lo = RNE fp16 of residual (~2^-22 rel)
__device__ __forceinline__ void fsplit_h(float f, unsigned short& hi, unsigned short& lo){
    __half h = __float2half_rn(f);
    hi = __half_as_ushort(h);
    lo = __half_as_ushort(__float2half_rn(f - __half2float(h)));
}
// split pair (a,b) -> fp16 hi/lo dwords, a in low half
__device__ __forceinline__ void fsplit2h(float a, float b, unsigned int& hpk, unsigned int& lpk){
    hpk = pkh2(a, b);
    lpk = pkh2(a - h2f((unsigned short)hpk), b - h2f((unsigned short)(hpk >> 16)));
}
// split 8 fp32 into fp16 hi/lo half8
__device__ __forceinline__ void split8h(f32x4 p0, f32x4 p1, half8& h, half8& l){
    unsigned int h01 = pkh2(p0[0], p0[1]);
    unsigned int h23 = pkh2(p0[2], p0[3]);
    unsigned int h45 = pkh2(p1[0], p1[1]);
    unsigned int h67 = pkh2(p1[2], p1[3]);
    unsigned int l01 = pkh2(p0[0] - h2f((unsigned short)h01), p0[1] - h2f((unsigned short)(h01 >> 16)));
    unsigned int l23 = pkh2(p0[2] - h2f((unsigned short)h23), p0[3] - h2f((unsigned short)(h23 >> 16)));
    unsigned int l45 = pkh2(p1[0] - h2f((unsigned short)h45), p1[1] - h2f((unsigned short)(h45 >> 16)));
    unsigned int l67 = pkh2(p1[2] - h2f((unsigned short)h67), p1[3] - h2f((unsigned short)(h67 >> 16)));
    i32x4 hv = {(int)h01, (int)h23, (int)h45, (int)h67};
    i32x4 lv = {(int)l01, (int)l23, (int)l45, (int)l67};
    h = __builtin_bit_cast(half8, hv);
    l = __builtin_bit_cast(half8, lv);
}

// ---------------- setup kernel: weight fragments (all fp16 hi/lo) ----------------
__global__ void prep_frags(const float* __restrict__ w1,
                           const float* __restrict__ w2g,
                           const float* __restrict__ w2s,
                           unsigned char* __restrict__ ws)
{
    const int t = blockIdx.x * 256 + threadIdx.x;   // 0..5119
    if (t < 4096) {                                  // W2: f = ((wv*2+nt)*4+kt)*2+h
        const int lane = t & 63, f = t >> 6;
        const int h = f & 1, kt = (f >> 1) & 3, nt = (f >> 3) & 1, wv = f >> 4;
        const int lr = lane & 15, lg = lane >> 4;
        const int col = wv*32 + nt*16 + lr;
        const float* src = (col < C2) ? (w2g + col) : (w2s + (col - C2));
        short8 out;
        #pragma unroll
        for (int e = 0; e < 8; ++e) {
            // H1 physical col p = kt*32 + w holds logical col (w>>1) + 16*(w&1)
            const int w = lg*8 + e;
            const int kl = kt*32 + (w >> 1) + ((w & 1) << 4);
            unsigned short hh, ll;
            fsplit_h(src[(size_t)kl * C2], hh, ll);
            out[e] = (short)(h ? ll : hh);
        }
        *(short8*)(ws + (size_t)f*1024 + lane*16) = out;
    } else if (t < 5120) {                           // W1: f = (wv*2+nt)*2+h (no perm)
        const int u = t - 4096;
        const int lane = u & 63, f = u >> 6;
        const int h = f & 1, nt = (f >> 1) & 1, wv = f >> 2;
        const int lr = lane & 15, lg = lane >> 4;
        short8 out = {0,0,0,0,0,0,0,0};
        if (lane < 32) {
            const int col = wv*32 + nt*16 + lr;
            #pragma unroll
            for (int e = 0; e < 8; ++e) {
                unsigned short hh, ll;
                fsplit_h(w1[(size_t)(lg*8 + e) * C1 + col], hh, ll);
                out[e] = (short)(h ? ll : hh);
            }
        }
        *(short8*)(ws + WS1_OFF + (size_t)f*1024 + lane*16) = out;
    }
}

// ---------------- main fused kernel ----------------
// LDS: 26,624 B total -> 6 blocks/CU (6 x 26,624 = 159,744 < 163,840, 4 KB slack —
// r16 lesson: exact-fit at the pool boundary does NOT allocate; keep margin).
// Ts is now fp16 SINGLE, same [col][48] layout/stride as Tg.
// sPool/sG1 alias into H1 (dead after phase 3; barriers separate all uses).
union __align__(16) R1u {
    struct { float A[GPB*NNODE*NNODE]; float X[GPB*NNODE*FIN]; } stg;  // 6688 B
    unsigned short ts[C2*TGS];                                          // 7168 B (fp16 single)
};
union __align__(16) R2u {
    struct { unsigned short hi[RP][FIN]; unsigned short lo[RP][FIN]; } ax; // 3072 B (fp16 bits)
    unsigned short tg[C2*TGS];                                             // 7168 B (fp16 single)
};

__global__ __launch_bounds__(THREADS, 4) void gnn_fused(
    const float* __restrict__ x, const float* __restrict__ a,
    const float* __restrict__ b1, const float* __restrict__ b2,
    const float* __restrict__ wf1, const float* __restrict__ bf1,
    const float* __restrict__ wf2, const float* __restrict__ bf2,
    const unsigned char* __restrict__ ws,
    float* __restrict__ out)
{
    __shared__ R1u R1;                                   // 7168 B
    __shared__ R2u R2;                                   // 7168 B
    __shared__ __align__(16) unsigned short H1[RP*C1];   // 12288 B fp16 (interleaved+swz)
    // total = 26,624 B -> 6 blocks/CU
    float* sPool = (float*)H1;                // [GPB][C2], phases 4-6 (H1 dead)
    float* sG1   = (float*)H1 + GPB*C2;       // [GPB][C3], phase 6

    const int tid  = threadIdx.x;
    const int lane = tid & 63;
    const int wv   = tid >> 6;
    const int lr   = lane & 15;
    const int lg   = lane >> 4;

    // ---- stage A, X fp32 (float4 coalesced) ----
    const float* ga = a + (size_t)blockIdx.x * (GPB*NNODE*NNODE);
    const float* gx = x + (size_t)blockIdx.x * (GPB*NNODE*FIN);
    if (tid < (GPB*NNODE*NNODE)/4) ((float4*)R1.stg.A)[tid] = ((const float4*)ga)[tid];
    if (tid < (GPB*NNODE*FIN)/4)   ((float4*)R1.stg.X)[tid] = ((const float4*)gx)[tid];
    __syncthreads();

    // ---- A-operand fragments fp16 hi/lo in registers (phases 1 and 4) ----
    const int g1 = wv & 1;
    half8 ah[2], al[2];
    #pragma unroll
    for (int m = 0; m < 2; ++m) {
        int row = lr + 16*m; if (row >= NNODE) row = NNODE-1;   // clamped rows discarded
        const float* src = R1.stg.A + g1*(NNODE*NNODE) + row*NNODE;
        f32x4 p0, p1;
        #pragma unroll
        for (int e = 0; e < 4; ++e) {
            const int k0 = lg*8 + e, k1 = lg*8 + 4 + e;
            p0[e] = (k0 < NNODE) ? src[k0] : 0.f;
            p1[e] = (k1 < NNODE) ? src[k1] : 0.f;
        }
        split8h(p0, p1, ah[m], al[m]);
    }

    // ---- Phase 1: AX = A @ X via fp16x3 MFMA; rows g*24+n, pad rows zeroed ----
    {
        f32x4 p0, p1;
        #pragma unroll
        for (int e = 0; e < 4; ++e) {
            const int k0 = lg*8 + e, k1 = lg*8 + 4 + e;
            p0[e] = (k0 < NNODE) ? R1.stg.X[g1*(NNODE*FIN) + k0*FIN + lr] : 0.f;
            p1[e] = (k1 < NNODE) ? R1.stg.X[g1*(NNODE*FIN) + k1*FIN + lr] : 0.f;
        }
        half8 xh, xl;
        split8h(p0, p1, xh, xl);
        const int m1 = wv >> 1;
        f32x4 d = {0.f,0.f,0.f,0.f};
        d = __builtin_amdgcn_mfma_f32_16x16x32_f16(ah[m1], xh, d, 0, 0, 0);
        d = __builtin_amdgcn_mfma_f32_16x16x32_f16(ah[m1], xl, d, 0, 0, 0);
        d = __builtin_amdgcn_mfma_f32_16x16x32_f16(al[m1], xh, d, 0, 0, 0);
        unsigned int hp01, lp01, hp23, lp23;
        fsplit2h(d[0], d[1], hp01, lp01);
        fsplit2h(d[2], d[3], hp23, lp23);
        #pragma unroll
        for (int r = 0; r < 4; ++r) {
            const int n = m1*16 + lg*4 + r;
            if (n < RPAD) {
                const unsigned int hp = (r < 2) ? hp01 : hp23;
                const unsigned int lp = (r < 2) ? lp01 : lp23;
                const int sh = (r & 1) * 16;
                R2.ax.hi[g1*RPAD + n][lr] = (n < NNODE) ? (unsigned short)(hp >> sh) : (unsigned short)0;
                R2.ax.lo[g1*RPAD + n][lr] = (n < NNODE) ? (unsigned short)(lp >> sh) : (unsigned short)0;
            }
        }
    }
    __syncthreads();

    // ---- Phase 2: H1 = relu(AX@W1+b1) via fp16x3; store fp16 INTERLEAVED b32 ----
    {
        const unsigned char* w1f = ws + WS1_OFF + (size_t)wv*4096 + lane*16;
        const half8 b1h0 = *(const half8*)(w1f + 0);
        const half8 b1l0 = *(const half8*)(w1f + 1024);
        const half8 b1h1 = *(const half8*)(w1f + 2048);
        const half8 b1l1 = *(const half8*)(w1f + 3072);
        const float bb10 = b1[wv*32 + lr];
        const float bb11 = b1[wv*32 + 16 + lr];
        const int p0c = wv*32 + 2*lr;   // physical col pair (p0c, p0c+1)
        #pragma unroll
        for (int mt = 0; mt < MT; ++mt) {
            half8 axh = {0,0,0,0,0,0,0,0}, axl = {0,0,0,0,0,0,0,0};
            if (lane < 32) {   // K=16 padded to 32
                axh = *(const half8*)&R2.ax.hi[mt*16 + lr][lg*8];
                axl = *(const half8*)&R2.ax.lo[mt*16 + lr][lg*8];
            }
            f32x4 a0 = {0.f,0.f,0.f,0.f}, a1 = {0.f,0.f,0.f,0.f};
            a0 = __builtin_amdgcn_mfma_f32_16x16x32_f16(axh, b1h0, a0, 0, 0, 0);
            a0 = __builtin_amdgcn_mfma_f32_16x16x32_f16(axh, b1l0, a0, 0, 0, 0);
            a0 = __builtin_amdgcn_mfma_f32_16x16x32_f16(axl, b1h0, a0, 0, 0, 0);
            a1 = __builtin_amdgcn_mfma_f32_16x16x32_f16(axh, b1h1, a1, 0, 0, 0);
            a1 = __builtin_amdgcn_mfma_f32_16x16x32_f16(axh, b1l1, a1, 0, 0, 0);
            a1 = __builtin_amdgcn_mfma_f32_16x16x32_f16(axl, b1h1, a1, 0, 0, 0);
            #pragma unroll
            for (int r = 0; r < 4; ++r) {
                const int row = mt*16 + lg*4 + r;    // all 48 rows (pads = relu(b1), finite)
                float v0 = a0[r] + bb10; v0 = v0 > 0.f ? v0 : 0.f;
                float v1 = a1[r] + bb11; v1 = v1 > 0.f ? v1 : 0.f;
                const int idx = row*C1 + (p0c ^ ((row & 7) << 3));
                *(unsigned int*)&H1[idx] = pkh2(v0, v1);   // v0 -> low = physical p0c
            }
        }
    }
    __syncthreads();

    // ---- Phase 3: T = H1 @ [w2g|w2s], fp16 MFMA x2 products (dominant GEMM) ----
    {
        f32x4 acc[MT][2];
        #pragma unroll
        for (int mt = 0; mt < MT; ++mt) {
            acc[mt][0] = (f32x4){0.f,0.f,0.f,0.f};
            acc[mt][1] = (f32x4){0.f,0.f,0.f,0.f};
        }
        const unsigned char* w2f = ws + (size_t)wv*16384 + lane*16;
        const int swz = (lr & 7) << 3;
        #pragma unroll
        for (int kt = 0; kt < 4; ++kt) {
            const unsigned char* wk = w2f + kt*2048;
            const half8 w0h  = *(const half8*)(wk + 0);
            const half8 w0l  = *(const half8*)(wk + 1024);
            const half8 w1h_ = *(const half8*)(wk + 8192);
            const half8 w1l_ = *(const half8*)(wk + 8192 + 1024);
            #pragma unroll
            for (int mt = 0; mt < MT; ++mt) {
                const int uoff = (mt*16 + lr)*C1 + ((kt*32 + lg*8) ^ swz);
                const half8 hh = *(const half8*)&H1[uoff];
                acc[mt][0] = __builtin_amdgcn_mfma_f32_16x16x32_f16(hh, w0h,  acc[mt][0], 0, 0, 0);
                acc[mt][0] = __builtin_amdgcn_mfma_f32_16x16x32_f16(hh, w0l,  acc[mt][0], 0, 0, 0);
                acc[mt][1] = __builtin_amdgcn_mfma_f32_16x16x32_f16(hh, w1h_, acc[mt][1], 0, 0, 0);
                acc[mt][1] = __builtin_amdgcn_mfma_f32_16x16x32_f16(hh, w1l_, acc[mt][1], 0, 0, 0);
            }
        }
        __syncthreads();   // all H1 reads done -> overwrite unions with T
        if (wv < 2) {
            // cols 0..63 = Tg: fp16 SINGLE, 4 consecutive padded rows -> one b64 write
            #pragma unroll
            for (int mt = 0; mt < MT; ++mt) {
                const int cr0 = mt*16 + lg*4;
                #pragma unroll
                for (int nt = 0; nt < 2; ++nt) {
                    const int col = wv*32 + nt*16 + lr;
                    uint2 hv;
                    hv.x = pkh2(acc[mt][nt][0], acc[mt][nt][1]);
                    hv.y = pkh2(acc[mt][nt][2], acc[mt][nt][3]);
                    *(uint2*)&R2.tg[col*TGS + cr0] = hv;
                }
            }
        } else {
            // cols 64..127 = Ts: fp16 SINGLE, same layout as Tg
            #pragma unroll
            for (int mt = 0; mt < MT; ++mt) {
                const int cr0 = mt*16 + lg*4;
                #pragma unroll
                for (int nt = 0; nt < 2; ++nt) {
                    const int col = (wv-2)*32 + nt*16 + lr;
                    uint2 hv;
                    hv.x = pkh2(acc[mt][nt][0], acc[mt][nt][1]);
                    hv.y = pkh2(acc[mt][nt][2], acc[mt][nt][3]);
                    *(uint2*)&R1.ts[col*TGS + cr0] = hv;
                }
            }
        }
    }
    __syncthreads();

    // ---- Phase 4+5: H2 = relu(A@Tg + Ts + b2); pool. acc init = Ts (fp16) ----
    {
        const int g4 = wv & 1;
        const int ntBase = (wv >> 1) * 2;
        float pool[2] = {0.f, 0.f};
        #pragma unroll
        for (int ntI = 0; ntI < 2; ++ntI) {
            const int col = (ntBase + ntI)*16 + lr;
            const unsigned short* tsb = &R1.ts[col*TGS + g4*RPAD];
            f32x4 acc4[2];
            {
                uint2 v0 = *(const uint2*)(tsb + lg*4);        // rows lg*4..+3   (m=0)
                uint2 v1 = *(const uint2*)(tsb + 16 + lg*4);   // rows 16+lg*4..+3 (m=1; n>=22 masked)
                acc4[0][0] = h2f((unsigned short)v0.x); acc4[0][1] = h2f((unsigned short)(v0.x >> 16));
                acc4[0][2] = h2f((unsigned short)v0.y); acc4[0][3] = h2f((unsigned short)(v0.y >> 16));
                acc4[1][0] = h2f((unsigned short)v1.x); acc4[1][1] = h2f((unsigned short)(v1.x >> 16));
                acc4[1][2] = h2f((unsigned short)v1.y); acc4[1][3] = h2f((unsigned short)(v1.y >> 16));
            }
            half8 bh = {0,0,0,0,0,0,0,0};
            if (lg < 3) {   // k=24..31 would alias other graph: keep zero regs
                bh = *(const half8*)&R2.tg[col*TGS + g4*RPAD + lg*8];
            }
            #pragma unroll
            for (int m = 0; m < 2; ++m) {
                acc4[m] = __builtin_amdgcn_mfma_f32_16x16x32_f16(ah[m], bh, acc4[m], 0, 0, 0);
                acc4[m] = __builtin_amdgcn_mfma_f32_16x16x32_f16(al[m], bh, acc4[m], 0, 0, 0);
            }
            const float bb = b2[col];
            #pragma unroll
            for (int m = 0; m < 2; ++m) {
                #pragma unroll
                for (int r = 0; r < 4; ++r) {
                    const int n = m*16 + lg*4 + r;
                    if (n < NNODE) {
                        float v = acc4[m][r] + bb;
                        pool[ntI] += (v > 0.f ? v : 0.f);
                    }
                }
            }
            pool[ntI] += __shfl_xor(pool[ntI], 16);
            pool[ntI] += __shfl_xor(pool[ntI], 32);
        }
        if (lane < 16) {
            sPool[g4*C2 + (ntBase + 0)*16 + lr] = pool[0];
            sPool[g4*C2 + (ntBase + 1)*16 + lr] = pool[1];
        }
    }
    __syncthreads();

    // ---- Phase 6: head ----
    if (tid < GPB*C3) {
        const int g = tid >> 5, j = tid & 31;
        float s = bf1[j];
        #pragma unroll
        for (int c = 0; c < C2; ++c) s += sPool[g*C2 + c] * wf1[c*C3 + j];
        sG1[g*C3 + j] = s > 0.f ? s : 0.f;
    }
    __syncthreads();
    if (tid < GPB) {
        float s = bf2[0];
        #pragma unroll
        for (int j = 0; j < C3; ++j) s += sG1[tid*C3 + j] * wf2[j];
        out[(size_t)blockIdx.x*GPB + tid] = 1.f / (1.f + expf(-s));
    }
}

extern "C" void kernel_launch(void* const* d_in, const int* in_sizes, int n_in,
                              void* d_out, int out_size, void* d_ws, size_t ws_size,
                              hipStream_t stream) {
    const float* x   = (const float*)d_in[0];
    const float* a   = (const float*)d_in[1];
    const float* w1  = (const float*)d_in[2];
    const float* b1  = (const float*)d_in[3];
    const float* w2g = (const float*)d_in[4];
    const float* w2s = (const float*)d_in[5];
    const float* b2  = (const float*)d_in[6];
    const float* wf1 = (const float*)d_in[7];
    const float* bf1 = (const float*)d_in[8];
    const float* wf2 = (const float*)d_in[9];
    const float* bf2 = (const float*)d_in[10];
    float* out = (float*)d_out;
    unsigned char* ws = (unsigned char*)d_ws;

    prep_frags<<<dim3(20), dim3(256), 0, stream>>>(w1, w2g, w2s, ws);

    const int B = in_sizes[0] / (NNODE * FIN);  // 32768
    gnn_fused<<<dim3(B / GPB), dim3(THREADS), 0, stream>>>(
        x, a, b1, b2, wf1, bf1, wf2, bf2, ws, out);
}

// Round 19
// 129.108 us; speedup vs baseline: 1.2205x; 1.0201x over previous
//
#include <hip/hip_runtime.h>
#include <hip/hip_fp16.h>
#include <math.h>

#define NNODE 22
#define FIN 16
#define C1 128
#define C2 64
#define C3 32
#define GPB 2              // graphs per block
#define RPAD 24            // padded rows per graph (rows 22,23 = pad)
#define RP 48              // total padded rows = 3 M-tiles of 16
#define MT 3
#define TGS 56             // Tg/Ts column stride (ushorts): 112B = 16B-aligned, 2-way banks
#define THREADS 256

typedef __attribute__((ext_vector_type(8))) short short8;
typedef __attribute__((ext_vector_type(8))) _Float16 half8;
typedef __attribute__((ext_vector_type(4))) float f32x4;
typedef __attribute__((ext_vector_type(4))) int i32x4;

#define WS2_BYTES (64*64*16)
#define WS1_OFF   WS2_BYTES

// ---- fp16 helpers (all RNE via documented intrinsics; asm cvt failed r7-8) ----
__device__ __forceinline__ float h2f(unsigned short u){
    return __half2float(__ushort_as_half(u));
}
__device__ __forceinline__ unsigned int pkh2(float a, float b){   // 2x fp16 RNE pack
    __half2 h = __float22half2_rn(float2{a, b});                  // a -> low 16
    unsigned int r;
    __builtin_memcpy(&r, &h, 4);
    return r;
}
// fp16 split (scalar, prep): hi RNE fp16, lo = RNE fp16 of residual (~2^-22 rel)
__device__ __forceinline__ void fsplit_h(float f, unsigned short& hi, unsigned short& lo){
    __half h = __float2half_rn(f);
    hi = __half_as_ushort(h);
    lo = __half_as_ushort(__float2half_rn(f - __half2float(h)));
}
// split 8 fp32 into fp16 hi/lo half8
__device__ __forceinline__ void split8h(f32x4 p0, f32x4 p1, half8& h, half8& l){
    unsigned int h01 = pkh2(p0[0], p0[1]);
    unsigned int h23 = pkh2(p0[2], p0[3]);
    unsigned int h45 = pkh2(p1[0], p1[1]);
    unsigned int h67 = pkh2(p1[2], p1[3]);
    unsigned int l01 = pkh2(p0[0] - h2f((unsigned short)h01), p0[1] - h2f((unsigned short)(h01 >> 16)));
    unsigned int l23 = pkh2(p0[2] - h2f((unsigned short)h23), p0[3] - h2f((unsigned short)(h23 >> 16)));
    unsigned int l45 = pkh2(p1[0] - h2f((unsigned short)h45), p1[1] - h2f((unsigned short)(h45 >> 16)));
    unsigned int l67 = pkh2(p1[2] - h2f((unsigned short)h67), p1[3] - h2f((unsigned short)(h67 >> 16)));
    i32x4 hv = {(int)h01, (int)h23, (int)h45, (int)h67};
    i32x4 lv = {(int)l01, (int)l23, (int)l45, (int)l67};
    h = __builtin_bit_cast(half8, hv);
    l = __builtin_bit_cast(half8, lv);
}

// ---------------- setup kernel: weight fragments (all fp16 hi/lo) ----------------
__global__ void prep_frags(const float* __restrict__ w1,
                           const float* __restrict__ w2g,
                           const float* __restrict__ w2s,
                           unsigned char* __restrict__ ws)
{
    const int t = blockIdx.x * 256 + threadIdx.x;   // 0..5119
    if (t < 4096) {                                  // W2: f = ((wv*2+nt)*4+kt)*2+h
        const int lane = t & 63, f = t >> 6;
        const int h = f & 1, kt = (f >> 1) & 3, nt = (f >> 3) & 1, wv = f >> 4;
        const int lr = lane & 15, lg = lane >> 4;
        const int col = wv*32 + nt*16 + lr;
        const float* src = (col < C2) ? (w2g + col) : (w2s + (col - C2));
        short8 out;
        #pragma unroll
        for (int e = 0; e < 8; ++e) {
            // H1 physical col p = kt*32 + w holds logical col (w>>1) + 16*(w&1)
            const int w = lg*8 + e;
            const int kl = kt*32 + (w >> 1) + ((w & 1) << 4);
            unsigned short hh, ll;
            fsplit_h(src[(size_t)kl * C2], hh, ll);
            out[e] = (short)(h ? ll : hh);
        }
        *(short8*)(ws + (size_t)f*1024 + lane*16) = out;
    } else if (t < 5120) {                           // W1: f = (wv*2+nt)*2+h (no perm)
        const int u = t - 4096;
        const int lane = u & 63, f = u >> 6;
        const int h = f & 1, nt = (f >> 1) & 1, wv = f >> 2;
        const int lr = lane & 15, lg = lane >> 4;
        short8 out = {0,0,0,0,0,0,0,0};
        if (lane < 32) {
            const int col = wv*32 + nt*16 + lr;
            #pragma unroll
            for (int e = 0; e < 8; ++e) {
                unsigned short hh, ll;
                fsplit_h(w1[(size_t)(lg*8 + e) * C1 + col], hh, ll);
                out[e] = (short)(h ? ll : hh);
            }
        }
        *(short8*)(ws + WS1_OFF + (size_t)f*1024 + lane*16) = out;
    }
}

// ---------------- main fused kernel ----------------
// r19 = r17 (131.7us, absmax 0.0117) + AX-single.
// Precision rule (r18 lesson): single-fp16 only where the MFMA partner operand
// is sign-symmetric (cancellation). AX-lo's partner W1 is sign-symmetric, K=16
// -> safe. W2-lo's partner H1 is ALL-POSITIVE, K=128 -> W2 must stay hi/lo pair.
union __align__(16) R1u {
    struct { float A[GPB*NNODE*NNODE]; float X[GPB*NNODE*FIN]; } stg;  // 6688 B
    unsigned short ts[C2*TGS];                                          // 7168 B (fp16 single)
};
union __align__(16) R2u {
    unsigned short ax[RP][FIN];                                         // 1536 B (fp16 single)
    unsigned short tg[C2*TGS];                                          // 7168 B (fp16 single)
};

__global__ __launch_bounds__(THREADS, 4) void gnn_fused(
    const float* __restrict__ x, const float* __restrict__ a,
    const float* __restrict__ b1, const float* __restrict__ b2,
    const float* __restrict__ wf1, const float* __restrict__ bf1,
    const float* __restrict__ wf2, const float* __restrict__ bf2,
    const unsigned char* __restrict__ ws,
    float* __restrict__ out)
{
    __shared__ R1u R1;                                   // 7168 B
    __shared__ R2u R2;                                   // 7168 B
    __shared__ __align__(16) unsigned short H1[RP*C1];   // 12288 B fp16 (interleaved+swz)
    // total = 26,624 B
    float* sPool = (float*)H1;                // [GPB][C2], phases 4-6 (H1 dead)
    float* sG1   = (float*)H1 + GPB*C2;       // [GPB][C3], phase 6

    const int tid  = threadIdx.x;
    const int lane = tid & 63;
    const int wv   = tid >> 6;
    const int lr   = lane & 15;
    const int lg   = lane >> 4;

    // ---- stage A, X fp32 (float4 coalesced) ----
    const float* ga = a + (size_t)blockIdx.x * (GPB*NNODE*NNODE);
    const float* gx = x + (size_t)blockIdx.x * (GPB*NNODE*FIN);
    if (tid < (GPB*NNODE*NNODE)/4) ((float4*)R1.stg.A)[tid] = ((const float4*)ga)[tid];
    if (tid < (GPB*NNODE*FIN)/4)   ((float4*)R1.stg.X)[tid] = ((const float4*)gx)[tid];
    __syncthreads();

    // ---- A-operand fragments fp16 hi/lo in registers (phases 1 and 4) ----
    const int g1 = wv & 1;
    half8 ah[2], al[2];
    #pragma unroll
    for (int m = 0; m < 2; ++m) {
        int row = lr + 16*m; if (row >= NNODE) row = NNODE-1;   // clamped rows discarded
        const float* src = R1.stg.A + g1*(NNODE*NNODE) + row*NNODE;
        f32x4 p0, p1;
        #pragma unroll
        for (int e = 0; e < 4; ++e) {
            const int k0 = lg*8 + e, k1 = lg*8 + 4 + e;
            p0[e] = (k0 < NNODE) ? src[k0] : 0.f;
            p1[e] = (k1 < NNODE) ? src[k1] : 0.f;
        }
        split8h(p0, p1, ah[m], al[m]);
    }

    // ---- Phase 1: AX = A @ X via fp16x3 MFMA; store fp16 SINGLE ----
    {
        f32x4 p0, p1;
        #pragma unroll
        for (int e = 0; e < 4; ++e) {
            const int k0 = lg*8 + e, k1 = lg*8 + 4 + e;
            p0[e] = (k0 < NNODE) ? R1.stg.X[g1*(NNODE*FIN) + k0*FIN + lr] : 0.f;
            p1[e] = (k1 < NNODE) ? R1.stg.X[g1*(NNODE*FIN) + k1*FIN + lr] : 0.f;
        }
        half8 xh, xl;
        split8h(p0, p1, xh, xl);
        const int m1 = wv >> 1;
        f32x4 d = {0.f,0.f,0.f,0.f};
        d = __builtin_amdgcn_mfma_f32_16x16x32_f16(ah[m1], xh, d, 0, 0, 0);
        d = __builtin_amdgcn_mfma_f32_16x16x32_f16(ah[m1], xl, d, 0, 0, 0);
        d = __builtin_amdgcn_mfma_f32_16x16x32_f16(al[m1], xh, d, 0, 0, 0);
        const unsigned int hp01 = pkh2(d[0], d[1]);
        const unsigned int hp23 = pkh2(d[2], d[3]);
        #pragma unroll
        for (int r = 0; r < 4; ++r) {
            const int n = m1*16 + lg*4 + r;
            if (n < RPAD) {
                const unsigned int hp = (r < 2) ? hp01 : hp23;
                const int sh = (r & 1) * 16;
                R2.ax[g1*RPAD + n][lr] = (n < NNODE) ? (unsigned short)(hp >> sh) : (unsigned short)0;
            }
        }
    }
    __syncthreads();

    // ---- Phase 2: H1 = relu(AX@W1+b1), AX single x W1 pair; fp16 INTERLEAVED ----
    {
        const unsigned char* w1f = ws + WS1_OFF + (size_t)wv*4096 + lane*16;
        const half8 b1h0 = *(const half8*)(w1f + 0);
        const half8 b1l0 = *(const half8*)(w1f + 1024);
        const half8 b1h1 = *(const half8*)(w1f + 2048);
        const half8 b1l1 = *(const half8*)(w1f + 3072);
        const float bb10 = b1[wv*32 + lr];
        const float bb11 = b1[wv*32 + 16 + lr];
        const int p0c = wv*32 + 2*lr;   // physical col pair (p0c, p0c+1)
        #pragma unroll
        for (int mt = 0; mt < MT; ++mt) {
            half8 axv = {0,0,0,0,0,0,0,0};
            if (lane < 32) {   // K=16 padded to 32
                axv = *(const half8*)&R2.ax[mt*16 + lr][lg*8];
            }
            f32x4 a0 = {0.f,0.f,0.f,0.f}, a1 = {0.f,0.f,0.f,0.f};
            a0 = __builtin_amdgcn_mfma_f32_16x16x32_f16(axv, b1h0, a0, 0, 0, 0);
            a0 = __builtin_amdgcn_mfma_f32_16x16x32_f16(axv, b1l0, a0, 0, 0, 0);
            a1 = __builtin_amdgcn_mfma_f32_16x16x32_f16(axv, b1h1, a1, 0, 0, 0);
            a1 = __builtin_amdgcn_mfma_f32_16x16x32_f16(axv, b1l1, a1, 0, 0, 0);
            #pragma unroll
            for (int r = 0; r < 4; ++r) {
                const int row = mt*16 + lg*4 + r;    // all 48 rows (pads = relu(b1), finite)
                float v0 = a0[r] + bb10; v0 = v0 > 0.f ? v0 : 0.f;
                float v1 = a1[r] + bb11; v1 = v1 > 0.f ? v1 : 0.f;
                const int idx = row*C1 + (p0c ^ ((row & 7) << 3));
                *(unsigned int*)&H1[idx] = pkh2(v0, v1);   // v0 -> low = physical p0c
            }
        }
    }
    __syncthreads();

    // ---- Phase 3: T = H1 @ [w2g|w2s], fp16 MFMA x2 products (W2 PAIR — r18) ----
    {
        f32x4 acc[MT][2];
        #pragma unroll
        for (int mt = 0; mt < MT; ++mt) {
            acc[mt][0] = (f32x4){0.f,0.f,0.f,0.f};
            acc[mt][1] = (f32x4){0.f,0.f,0.f,0.f};
        }
        const unsigned char* w2f = ws + (size_t)wv*16384 + lane*16;
        const int swz = (lr & 7) << 3;
        #pragma unroll
        for (int kt = 0; kt < 4; ++kt) {
            const unsigned char* wk = w2f + kt*2048;
            const half8 w0h  = *(const half8*)(wk + 0);
            const half8 w0l  = *(const half8*)(wk + 1024);
            const half8 w1h_ = *(const half8*)(wk + 8192);
            const half8 w1l_ = *(const half8*)(wk + 8192 + 1024);
            #pragma unroll
            for (int mt = 0; mt < MT; ++mt) {
                const int uoff = (mt*16 + lr)*C1 + ((kt*32 + lg*8) ^ swz);
                const half8 hh = *(const half8*)&H1[uoff];
                acc[mt][0] = __builtin_amdgcn_mfma_f32_16x16x32_f16(hh, w0h,  acc[mt][0], 0, 0, 0);
                acc[mt][0] = __builtin_amdgcn_mfma_f32_16x16x32_f16(hh, w0l,  acc[mt][0], 0, 0, 0);
                acc[mt][1] = __builtin_amdgcn_mfma_f32_16x16x32_f16(hh, w1h_, acc[mt][1], 0, 0, 0);
                acc[mt][1] = __builtin_amdgcn_mfma_f32_16x16x32_f16(hh, w1l_, acc[mt][1], 0, 0, 0);
            }
        }
        __syncthreads();   // all H1 reads done -> overwrite unions with T
        if (wv < 2) {
            // cols 0..63 = Tg: fp16 SINGLE, 4 consecutive padded rows -> one b64 write
            #pragma unroll
            for (int mt = 0; mt < MT; ++mt) {
                const int cr0 = mt*16 + lg*4;
                #pragma unroll
                for (int nt = 0; nt < 2; ++nt) {
                    const int col = wv*32 + nt*16 + lr;
                    uint2 hv;
                    hv.x = pkh2(acc[mt][nt][0], acc[mt][nt][1]);
                    hv.y = pkh2(acc[mt][nt][2], acc[mt][nt][3]);
                    *(uint2*)&R2.tg[col*TGS + cr0] = hv;
                }
            }
        } else {
            // cols 64..127 = Ts: fp16 SINGLE, same layout as Tg
            #pragma unroll
            for (int mt = 0; mt < MT; ++mt) {
                const int cr0 = mt*16 + lg*4;
                #pragma unroll
                for (int nt = 0; nt < 2; ++nt) {
                    const int col = (wv-2)*32 + nt*16 + lr;
                    uint2 hv;
                    hv.x = pkh2(acc[mt][nt][0], acc[mt][nt][1]);
                    hv.y = pkh2(acc[mt][nt][2], acc[mt][nt][3]);
                    *(uint2*)&R1.ts[col*TGS + cr0] = hv;
                }
            }
        }
    }
    __syncthreads();

    // ---- Phase 4+5: H2 = relu(A@Tg + Ts + b2); pool. acc init = Ts (fp16) ----
    {
        const int g4 = wv & 1;
        const int ntBase = (wv >> 1) * 2;
        float pool[2] = {0.f, 0.f};
        #pragma unroll
        for (int ntI = 0; ntI < 2; ++ntI) {
            const int col = (ntBase + ntI)*16 + lr;
            const unsigned short* tsb = &R1.ts[col*TGS + g4*RPAD];
            f32x4 acc4[2];
            {
                uint2 v0 = *(const uint2*)(tsb + lg*4);        // rows lg*4..+3   (m=0)
                uint2 v1 = *(const uint2*)(tsb + 16 + lg*4);   // rows 16+lg*4..+3 (m=1; n>=22 masked)
                acc4[0][0] = h2f((unsigned short)v0.x); acc4[0][1] = h2f((unsigned short)(v0.x >> 16));
                acc4[0][2] = h2f((unsigned short)v0.y); acc4[0][3] = h2f((unsigned short)(v0.y >> 16));
                acc4[1][0] = h2f((unsigned short)v1.x); acc4[1][1] = h2f((unsigned short)(v1.x >> 16));
                acc4[1][2] = h2f((unsigned short)v1.y); acc4[1][3] = h2f((unsigned short)(v1.y >> 16));
            }
            half8 bh = {0,0,0,0,0,0,0,0};
            if (lg < 3) {   // k=24..31 would alias other graph: keep zero regs
                bh = *(const half8*)&R2.tg[col*TGS + g4*RPAD + lg*8];
            }
            #pragma unroll
            for (int m = 0; m < 2; ++m) {
                acc4[m] = __builtin_amdgcn_mfma_f32_16x16x32_f16(ah[m], bh, acc4[m], 0, 0, 0);
                acc4[m] = __builtin_amdgcn_mfma_f32_16x16x32_f16(al[m], bh, acc4[m], 0, 0, 0);
            }
            const float bb = b2[col];
            #pragma unroll
            for (int m = 0; m < 2; ++m) {
                #pragma unroll
                for (int r = 0; r < 4; ++r) {
                    const int n = m*16 + lg*4 + r;
                    if (n < NNODE) {
                        float v = acc4[m][r] + bb;
                        pool[ntI] += (v > 0.f ? v : 0.f);
                    }
                }
            }
            pool[ntI] += __shfl_xor(pool[ntI], 16);
            pool[ntI] += __shfl_xor(pool[ntI], 32);
        }
        if (lane < 16) {
            sPool[g4*C2 + (ntBase + 0)*16 + lr] = pool[0];
            sPool[g4*C2 + (ntBase + 1)*16 + lr] = pool[1];
        }
    }
    __syncthreads();

    // ---- Phase 6: head ----
    if (tid < GPB*C3) {
        const int g = tid >> 5, j = tid & 31;
        float s = bf1[j];
        #pragma unroll
        for (int c = 0; c < C2; ++c) s += sPool[g*C2 + c] * wf1[c*C3 + j];
        sG1[g*C3 + j] = s > 0.f ? s : 0.f;
    }
    __syncthreads();
    if (tid < GPB) {
        float s = bf2[0];
        #pragma unroll
        for (int j = 0; j < C3; ++j) s += sG1[tid*C3 + j] * wf2[j];
        out[(size_t)blockIdx.x*GPB + tid] = 1.f / (1.f + expf(-s));
    }
}

extern "C" void kernel_launch(void* const* d_in, const int* in_sizes, int n_in,
                              void* d_out, int out_size, void* d_ws, size_t ws_size,
                              hipStream_t stream) {
    const float* x   = (const float*)d_in[0];
    const float* a   = (const float*)d_in[1];
    const float* w1  = (const float*)d_in[2];
    const float* b1  = (const float*)d_in[3];
    const float* w2g = (const float*)d_in[4];
    const float* w2s = (const float*)d_in[5];
    const float* b2  = (const float*)d_in[6];
    const float* wf1 = (const float*)d_in[7];
    const float* bf1 = (const float*)d_in[8];
    const float* wf2 = (const float*)d_in[9];
    const float* bf2 = (const float*)d_in[10];
    float* out = (float*)d_out;
    unsigned char* ws = (unsigned char*)d_ws;

    prep_frags<<<dim3(20), dim3(256), 0, stream>>>(w1, w2g, w2s, ws);

    const int B = in_sizes[0] / (NNODE * FIN);  // 32768
    gnn_fused<<<dim3(B / GPB), dim3(THREADS), 0, stream>>>(
        x, a, b1, b2, wf1, bf1, wf2, bf2, ws, out);
}